// Round 1
// baseline (3496.805 us; speedup 1.0000x reference)
//
#include <hip/hip_runtime.h>

typedef unsigned short u16;
typedef unsigned int   u32;
typedef __attribute__((ext_vector_type(4))) float f4;
typedef __attribute__((ext_vector_type(4))) float f32x4;
typedef __attribute__((ext_vector_type(8))) short s8v;      // MFMA bf16 frag (guide-verified)
typedef __attribute__((ext_vector_type(8))) u16  u16x8;
typedef __attribute__((ext_vector_type(4))) u16  u16x4;

#define DEV __device__ __forceinline__

DEV u16 f2bf(float f) {
  u32 u = __builtin_bit_cast(u32, f);
  u32 r = (u + 0x7fffu + ((u >> 16) & 1u)) >> 16;   // RNE truncate f32->bf16
  return (u16)r;
}
DEV float bf2f(u16 h) {
  u32 u = ((u32)h) << 16;
  return __builtin_bit_cast(float, u);
}

// ---------------------------------------------------------------------------
// GEMM: C[M,N] = A[M,K] * B + bias (+relu) (*rowscale)
//  PRECISE: A is f32, B f32; both split hi/lo bf16 -> 4 MFMA terms (~f32 acc.)
// !PRECISE: A is bf16 (u16), B f32 rounded to bf16 -> 1 MFMA term
//  BKMAJ:  B stored [N][K] (k-contiguous, "W.T" matmuls)
// !BKMAJ:  B stored [K][N] (n-contiguous, w1/w2/out_w)
// Tile 128x128, BK=32, 4 waves (2x2), mfma_f32_16x16x32_bf16.
// All M,N,K are multiples of 128/128/32 in this problem -> no edge guards.
// ---------------------------------------------------------------------------
template<bool PRECISE, bool BKMAJ, bool RELU, bool OUTBF16, bool ROWSCALE>
__global__ __launch_bounds__(256, 2) void gemm_k(
    const void* __restrict__ A_, const float* __restrict__ B_,
    const float* __restrict__ bias_, void* __restrict__ C_,
    const float* __restrict__ rowscale,
    int M, int N, int K,
    long aStride, long bStride, long biasStride, long cStride)
{
  constexpr int NB = PRECISE ? 2 : 1;
  __shared__ u16 As[NB][128][40];   // +8 pad: 2-way bank aliasing (free)
  __shared__ u16 Bs[NB][128][40];

  const int z   = blockIdx.z;
  const int tid = threadIdx.x;
  const int m0  = blockIdx.y * 128, n0 = blockIdx.x * 128;
  const float* Bb   = B_   + (long)z * bStride;
  const float* bias = bias_ + (long)z * biasStride;

  f32x4 acc[4][4];
  #pragma unroll
  for (int i = 0; i < 4; i++)
    #pragma unroll
    for (int j = 0; j < 4; j++)
      acc[i][j] = (f32x4){0.f, 0.f, 0.f, 0.f};

  const int lane = tid & 63, wid = tid >> 6;
  const int wm = (wid >> 1) * 64, wn = (wid & 1) * 64;
  const int lr = lane & 15, lg = lane >> 4;

  for (int k0 = 0; k0 < K; k0 += 32) {
    // ---------------- stage A (rows m0..m0+127, k0..k0+31) ----------------
    if constexpr (PRECISE) {
      const float* Af = (const float*)A_ + (long)z * aStride;
      const int m = tid >> 1, kk = (tid & 1) * 16;
      const float* src = Af + (long)(m0 + m) * K + k0 + kk;
      #pragma unroll
      for (int half = 0; half < 2; half++) {
        f4 v0 = *(const f4*)(src + half * 8);
        f4 v1 = *(const f4*)(src + half * 8 + 4);
        float vv[8] = {v0[0], v0[1], v0[2], v0[3], v1[0], v1[1], v1[2], v1[3]};
        u16x8 hi, lo;
        #pragma unroll
        for (int j = 0; j < 8; j++) {
          u16 hh = f2bf(vv[j]);
          hi[j] = hh;
          lo[j] = f2bf(vv[j] - bf2f(hh));
        }
        *(u16x8*)&As[0][m][kk + half * 8] = hi;
        *(u16x8*)&As[1][m][kk + half * 8] = lo;
      }
    } else {
      const u16* Ab = (const u16*)A_ + (long)z * aStride;
      const int m = tid >> 1, kk = (tid & 1) * 16;
      const u16* src = Ab + (long)(m0 + m) * K + k0 + kk;
      *(u16x8*)&As[0][m][kk]     = *(const u16x8*)(src);
      *(u16x8*)&As[0][m][kk + 8] = *(const u16x8*)(src + 8);
    }
    // ---------------- stage B ----------------
    if constexpr (BKMAJ) {
      const int n = tid >> 1, kk = (tid & 1) * 16;
      const float* src = Bb + (long)(n0 + n) * K + k0 + kk;
      #pragma unroll
      for (int half = 0; half < 2; half++) {
        f4 v0 = *(const f4*)(src + half * 8);
        f4 v1 = *(const f4*)(src + half * 8 + 4);
        float vv[8] = {v0[0], v0[1], v0[2], v0[3], v1[0], v1[1], v1[2], v1[3]};
        u16x8 hi, lo;
        #pragma unroll
        for (int j = 0; j < 8; j++) {
          u16 hh = f2bf(vv[j]);
          hi[j] = hh;
          if (PRECISE) lo[j] = f2bf(vv[j] - bf2f(hh));
        }
        *(u16x8*)&Bs[0][n][kk + half * 8] = hi;
        if constexpr (PRECISE) *(u16x8*)&Bs[1][n][kk + half * 8] = lo;
      }
    } else {
      // B [K][N]: lane-coalesced n, strided k; transpose into Bs[n][k]
      const int n = tid & 63, kk = (tid >> 6) * 8;
      #pragma unroll
      for (int it = 0; it < 2; it++) {
        const int nn = n + it * 64;
        const float* src = Bb + (long)(k0 + kk) * N + n0 + nn;
        u16x8 hi, lo;
        #pragma unroll
        for (int j = 0; j < 8; j++) {
          float v = src[(long)j * N];
          u16 hh = f2bf(v);
          hi[j] = hh;
          if (PRECISE) lo[j] = f2bf(v - bf2f(hh));
        }
        *(u16x8*)&Bs[0][nn][kk] = hi;
        if constexpr (PRECISE) *(u16x8*)&Bs[1][nn][kk] = lo;
      }
    }
    __syncthreads();
    // ---------------- compute ----------------
    s8v ah[4], bh[4];
    #pragma unroll
    for (int mi = 0; mi < 4; mi++) ah[mi] = *(const s8v*)&As[0][wm + mi * 16 + lr][lg * 8];
    #pragma unroll
    for (int ni = 0; ni < 4; ni++) bh[ni] = *(const s8v*)&Bs[0][wn + ni * 16 + lr][lg * 8];
    if constexpr (PRECISE) {
      s8v al[4], bl[4];
      #pragma unroll
      for (int mi = 0; mi < 4; mi++) al[mi] = *(const s8v*)&As[1][wm + mi * 16 + lr][lg * 8];
      #pragma unroll
      for (int ni = 0; ni < 4; ni++) bl[ni] = *(const s8v*)&Bs[1][wn + ni * 16 + lr][lg * 8];
      #pragma unroll
      for (int mi = 0; mi < 4; mi++)
        #pragma unroll
        for (int ni = 0; ni < 4; ni++) {
          f32x4 a = acc[mi][ni];
          a = __builtin_amdgcn_mfma_f32_16x16x32_bf16(al[mi], bl[ni], a, 0, 0, 0);
          a = __builtin_amdgcn_mfma_f32_16x16x32_bf16(al[mi], bh[ni], a, 0, 0, 0);
          a = __builtin_amdgcn_mfma_f32_16x16x32_bf16(ah[mi], bl[ni], a, 0, 0, 0);
          a = __builtin_amdgcn_mfma_f32_16x16x32_bf16(ah[mi], bh[ni], a, 0, 0, 0);
          acc[mi][ni] = a;
        }
    } else {
      #pragma unroll
      for (int mi = 0; mi < 4; mi++)
        #pragma unroll
        for (int ni = 0; ni < 4; ni++)
          acc[mi][ni] = __builtin_amdgcn_mfma_f32_16x16x32_bf16(ah[mi], bh[ni], acc[mi][ni], 0, 0, 0);
    }
    __syncthreads();
  }
  // ---------------- epilogue ----------------
  // C/D layout (verified m89): col = lane&15, row = (lane>>4)*4 + reg
  #pragma unroll
  for (int mi = 0; mi < 4; mi++) {
    const int gr0 = m0 + wm + mi * 16 + lg * 4;
    #pragma unroll
    for (int ni = 0; ni < 4; ni++) {
      const int gc = n0 + wn + ni * 16 + lr;
      const float bv = bias[gc];
      #pragma unroll
      for (int r = 0; r < 4; r++) {
        float v = acc[mi][ni][r] + bv;
        if constexpr (RELU) v = fmaxf(v, 0.f);
        if constexpr (ROWSCALE) v *= rowscale[(long)(gr0 + r) * 8 + z];
        const long idx = (long)z * cStride + (long)(gr0 + r) * N + gc;
        if constexpr (OUTBF16) ((u16*)C_)[idx] = f2bf(v);
        else                   ((float*)C_)[idx] = v;
      }
    }
  }
}

// ---------------------------------------------------------------------------
// Embedding: h[t][d] = emb[x[t]][d] + pos[t%512][d]; write f32 + bf16
// ---------------------------------------------------------------------------
__global__ __launch_bounds__(256) void embed_k(
    const int* __restrict__ x, const float* __restrict__ emb,
    const float* __restrict__ pos, float* __restrict__ h, u16* __restrict__ hb)
{
  const int t = blockIdx.x, d = threadIdx.x * 4;
  const int row = x[t];
  f4 e = *(const f4*)(emb + (long)row * 1024 + d);
  f4 p = *(const f4*)(pos + (long)(t & 511) * 1024 + d);
  f4 y = e + p;
  *(f4*)(h + (long)t * 1024 + d) = y;
  u16x4 yb = {f2bf(y[0]), f2bf(y[1]), f2bf(y[2]), f2bf(y[3])};
  *(u16x4*)(hb + (long)t * 1024 + d) = yb;
}

// ---------------------------------------------------------------------------
// Attention over the BATCH axis (faithful to source bug). One wave per (s,h).
// qkv f32 [B*S][3072]; o f32 [B*S][1024]. lane = head-dim c (HD=64).
// ---------------------------------------------------------------------------
__global__ __launch_bounds__(256) void attn_k(const float* __restrict__ qkv, float* __restrict__ o)
{
  const int wid = threadIdx.x >> 6, lane = threadIdx.x & 63;
  const int gid = blockIdx.x * 4 + wid;       // 0..8191
  const int s = gid >> 4, hh = gid & 15;
  float q[4], k[4], v[4];
  #pragma unroll
  for (int i = 0; i < 4; i++) {
    const long base = (long)(i * 512 + s) * 3072 + hh * 64 + lane;
    q[i] = qkv[base] * 0.125f;                // 1/sqrt(64)
    k[i] = qkv[base + 1024];
    v[i] = qkv[base + 2048];
  }
  float sc[4][4];
  #pragma unroll
  for (int i = 0; i < 4; i++)
    #pragma unroll
    for (int j = 0; j < 4; j++) sc[i][j] = q[i] * k[j];
  #pragma unroll
  for (int off = 32; off >= 1; off >>= 1)
    #pragma unroll
    for (int i = 0; i < 4; i++)
      #pragma unroll
      for (int j = 0; j < 4; j++) sc[i][j] += __shfl_xor(sc[i][j], off, 64);
  #pragma unroll
  for (int i = 0; i < 4; i++) {
    float m = fmaxf(fmaxf(sc[i][0], sc[i][1]), fmaxf(sc[i][2], sc[i][3]));
    float e0 = expf(sc[i][0] - m), e1 = expf(sc[i][1] - m);
    float e2 = expf(sc[i][2] - m), e3 = expf(sc[i][3] - m);
    float inv = 1.f / (e0 + e1 + e2 + e3);
    float outv = (e0 * v[0] + e1 * v[1] + e2 * v[2] + e3 * v[3]) * inv;
    o[(long)(i * 512 + s) * 1024 + hh * 64 + lane] = outv;
  }
}

// ---------------------------------------------------------------------------
// LayerNorm(h + sum_{i<NADD} add[i]) in-place on h; also writes bf16 copy.
// One block (256 thr) per row of 1024.
// ---------------------------------------------------------------------------
template<int NADD>
__global__ __launch_bounds__(256) void ln_k(
    float* __restrict__ h, const float* __restrict__ add, long addStride,
    const float* __restrict__ g, const float* __restrict__ b, u16* __restrict__ hb)
{
  const int t = blockIdx.x, tid = threadIdx.x;
  const long base = (long)t * 1024 + tid * 4;
  f4 x = *(const f4*)(h + base);
  #pragma unroll
  for (int i = 0; i < NADD; i++) x += *(const f4*)(add + (long)i * addStride + base);
  float s1 = x[0] + x[1] + x[2] + x[3];
  float s2 = x[0] * x[0] + x[1] * x[1] + x[2] * x[2] + x[3] * x[3];
  #pragma unroll
  for (int off = 32; off >= 1; off >>= 1) {
    s1 += __shfl_xor(s1, off, 64);
    s2 += __shfl_xor(s2, off, 64);
  }
  __shared__ float red[2][4];
  const int lane = tid & 63, wid = tid >> 6;
  if (lane == 0) { red[0][wid] = s1; red[1][wid] = s2; }
  __syncthreads();
  s1 = red[0][0] + red[0][1] + red[0][2] + red[0][3];
  s2 = red[1][0] + red[1][1] + red[1][2] + red[1][3];
  const float mu = s1 * (1.f / 1024.f);
  const float var = s2 * (1.f / 1024.f) - mu * mu;
  const float rstd = rsqrtf(var + 1e-5f);
  f4 gg = *(const f4*)(g + tid * 4);
  f4 bb = *(const f4*)(b + tid * 4);
  f4 y;
  #pragma unroll
  for (int c = 0; c < 4; c++) y[c] = (x[c] - mu) * rstd * gg[c] + bb[c];
  *(f4*)(h + base) = y;
  u16x4 yb = {f2bf(y[0]), f2bf(y[1]), f2bf(y[2]), f2bf(y[3])};
  *(u16x4*)(hb + base) = yb;
}

// ---------------------------------------------------------------------------
// Gating: probs = softmax(h@gw + gb); top2; comb[t][e] = renorm weight or 0;
// atomic-accumulate probs into lsum[8]. One wave per token.
// ---------------------------------------------------------------------------
__global__ __launch_bounds__(256) void gate_k(
    const float* __restrict__ h, const float* __restrict__ gw,
    const float* __restrict__ gb, float* __restrict__ comb, float* __restrict__ lsum)
{
  const int wid = threadIdx.x >> 6, lane = threadIdx.x & 63;
  const int t = blockIdx.x * 4 + wid;
  float acc[8] = {0.f, 0.f, 0.f, 0.f, 0.f, 0.f, 0.f, 0.f};
  for (int d = lane; d < 1024; d += 64) {
    const float hv = h[(long)t * 1024 + d];
    const f4* g4 = (const f4*)(gw + (long)d * 8);
    f4 g0 = g4[0], g1 = g4[1];
    acc[0] += hv * g0[0]; acc[1] += hv * g0[1]; acc[2] += hv * g0[2]; acc[3] += hv * g0[3];
    acc[4] += hv * g1[0]; acc[5] += hv * g1[1]; acc[6] += hv * g1[2]; acc[7] += hv * g1[3];
  }
  #pragma unroll
  for (int off = 32; off >= 1; off >>= 1)
    #pragma unroll
    for (int e = 0; e < 8; e++) acc[e] += __shfl_xor(acc[e], off, 64);
  float lg[8], ex[8], p[8];
  float mx = -1e30f;
  #pragma unroll
  for (int e = 0; e < 8; e++) { lg[e] = acc[e] + gb[e]; mx = fmaxf(mx, lg[e]); }
  float s = 0.f;
  #pragma unroll
  for (int e = 0; e < 8; e++) { ex[e] = expf(lg[e] - mx); s += ex[e]; }
  const float inv = 1.f / s;
  #pragma unroll
  for (int e = 0; e < 8; e++) p[e] = ex[e] * inv;
  // top-2, ties -> lowest index (lax.top_k semantics)
  int i1 = 0; float p1 = p[0];
  #pragma unroll
  for (int e = 1; e < 8; e++) { if (p[e] > p1) { p1 = p[e]; i1 = e; } }
  int i2 = -1; float p2 = -1e30f;
  #pragma unroll
  for (int e = 0; e < 8; e++) { if (e != i1 && p[e] > p2) { p2 = p[e]; i2 = e; } }
  const float e2 = expf(p2 - p1);           // softmax([p1,p2]) renorm, as source
  const float w1 = 1.f / (1.f + e2);
  const float w2 = e2 / (1.f + e2);
  if (lane < 8) {
    const float c = (lane == i1) ? w1 : ((lane == i2) ? w2 : 0.f);
    comb[(long)t * 8 + lane] = c;
    float myp = p[0];
    #pragma unroll
    for (int e = 1; e < 8; e++) myp = (lane == e) ? p[e] : myp;
    atomicAdd(&lsum[lane], myp);
  }
}

// ---------------------------------------------------------------------------
// Loss: total = sum_l E * var(lsum[l]/2048, ddof=1)
// ---------------------------------------------------------------------------
__global__ void loss_k(const float* __restrict__ lsum, float* __restrict__ out)
{
  if (threadIdx.x == 0 && blockIdx.x == 0) {
    float total = 0.f;
    #pragma unroll
    for (int l = 0; l < 2; l++) {
      float v[8]; float mean = 0.f;
      #pragma unroll
      for (int e = 0; e < 8; e++) { v[e] = lsum[l * 8 + e] * (1.f / 2048.f); mean += v[e]; }
      mean *= 0.125f;
      float var = 0.f;
      #pragma unroll
      for (int e = 0; e < 8; e++) { float d = v[e] - mean; var += d * d; }
      var *= (1.f / 7.f);
      total += 8.f * var;
    }
    *out = total;
  }
}

// ---------------------------------------------------------------------------
extern "C" void kernel_launch(void* const* d_in, const int* in_sizes, int n_in,
                              void* d_out, int out_size, void* d_ws, size_t ws_size,
                              hipStream_t stream)
{
  const int*   x    = (const int*)  d_in[0];
  const float* emb  = (const float*)d_in[1];
  const float* pos  = (const float*)d_in[2];
  const float* aiw  = (const float*)d_in[3];
  const float* aib  = (const float*)d_in[4];
  const float* aow  = (const float*)d_in[5];
  const float* aob  = (const float*)d_in[6];
  const float* gw   = (const float*)d_in[7];
  const float* gb   = (const float*)d_in[8];
  const float* w1   = (const float*)d_in[9];
  const float* b1   = (const float*)d_in[10];
  const float* w2   = (const float*)d_in[11];
  const float* b2   = (const float*)d_in[12];
  const float* ln1g = (const float*)d_in[13];
  const float* ln1b = (const float*)d_in[14];
  const float* ln2g = (const float*)d_in[15];
  const float* ln2b = (const float*)d_in[16];
  const float* outw = (const float*)d_in[17];
  const float* outb = (const float*)d_in[18];
  float* out = (float*)d_out;

  char* base = (char*)d_ws;
  size_t off = 0;
  auto carve = [&](size_t bytes) -> void* {
    void* r = base + off;
    off += (bytes + 255) & ~(size_t)255;
    return r;
  };
  float* h    = (float*)carve(2048L * 1024 * 4);        //  8 MiB f32 activation
  u16*   hb   = (u16*)  carve(2048L * 1024 * 2);        //  4 MiB bf16 activation
  float* qkv  = (float*)carve(2048L * 3072 * 4);        // 24 MiB
  float* ov   = (float*)carve(2048L * 1024 * 4);        //  8 MiB attention out
  float* af   = (float*)carve(2048L * 1024 * 4);        //  8 MiB attn proj out
  float* midf = (float*)carve(4L * 2048 * 4096 * 4);    // 128 MiB (f32 l0 / bf16 l1, 4-expert chunk)
  float* eo   = (float*)carve(8L * 2048 * 1024 * 4);    // 64 MiB weighted expert outs
  float* comb = (float*)carve(2048L * 8 * 4);
  float* lsum = (float*)carve(16 * 4);

  hipMemsetAsync(lsum, 0, 64, stream);
  embed_k<<<2048, 256, 0, stream>>>(x, emb, pos, h, hb);

  for (int l = 0; l < 2; l++) {
    // qkv = h @ aiw[l].T + aib[l]   (precise)
    gemm_k<true, true, false, false, false><<<dim3(24, 16, 1), 256, 0, stream>>>(
        h, aiw + (long)l * 3072 * 1024, aib + l * 3072, qkv, nullptr,
        2048, 3072, 1024, 0, 0, 0, 0);
    attn_k<<<2048, 256, 0, stream>>>(qkv, ov);
    // a = o @ aow[l].T + aob[l]     (precise)
    gemm_k<true, true, false, false, false><<<dim3(8, 16, 1), 256, 0, stream>>>(
        ov, aow + (long)l * 1024 * 1024, aob + l * 1024, af, nullptr,
        2048, 1024, 1024, 0, 0, 0, 0);
    ln_k<1><<<2048, 256, 0, stream>>>(h, af, 0, ln1g + l * 1024, ln1b + l * 1024, hb);
    gate_k<<<512, 256, 0, stream>>>(h, gw + (long)l * 1024 * 8, gb + l * 8, comb, lsum + l * 8);

    if (l == 0) {
      // layer-0 MoE feeds layer-1's gate -> precise path, f32 mid
      for (int c = 0; c < 2; c++) {
        gemm_k<true, false, true, false, false><<<dim3(32, 16, 4), 256, 0, stream>>>(
            h, w1 + ((long)l * 8 + c * 4) * 1024 * 4096, b1 + ((long)l * 8 + c * 4) * 4096,
            midf, nullptr, 2048, 4096, 1024, 0, 4096L * 1024, 4096, 2048L * 4096);
        gemm_k<true, false, false, false, true><<<dim3(8, 16, 4), 256, 0, stream>>>(
            midf, w2 + ((long)l * 8 + c * 4) * 4096 * 1024, b2 + ((long)l * 8 + c * 4) * 1024,
            eo + (long)c * 4 * 2048 * 1024, comb + c * 4,
            2048, 1024, 4096, 2048L * 4096, 1024L * 4096, 1024, 2048L * 1024);
      }
    } else {
      // layer-1 MoE only feeds logits -> 1x bf16 path
      u16* midb = (u16*)midf;
      for (int c = 0; c < 2; c++) {
        gemm_k<false, false, true, true, false><<<dim3(32, 16, 4), 256, 0, stream>>>(
            hb, w1 + ((long)l * 8 + c * 4) * 1024 * 4096, b1 + ((long)l * 8 + c * 4) * 4096,
            midb, nullptr, 2048, 4096, 1024, 0, 4096L * 1024, 4096, 2048L * 4096);
        gemm_k<false, false, false, false, true><<<dim3(8, 16, 4), 256, 0, stream>>>(
            midb, w2 + ((long)l * 8 + c * 4) * 4096 * 1024, b2 + ((long)l * 8 + c * 4) * 1024,
            eo + (long)c * 4 * 2048 * 1024, comb + c * 4,
            2048, 1024, 4096, 2048L * 4096, 1024L * 4096, 1024, 2048L * 1024);
      }
    }
    ln_k<8><<<2048, 256, 0, stream>>>(h, eo, 2048L * 1024, ln2g + l * 1024, ln2b + l * 1024, hb);
  }

  // logits = h @ out_w + out_b  (bf16 path)
  gemm_k<false, false, false, false, false><<<dim3(250, 16, 1), 256, 0, stream>>>(
      hb, outw, outb, out, nullptr, 2048, 32000, 1024, 0, 0, 0, 0);
  loss_k<<<1, 64, 0, stream>>>(lsum, out + 2048L * 32000);
}